// Round 7
// baseline (420.438 us; speedup 1.0000x reference)
//
#include <hip/hip_runtime.h>

typedef unsigned short u16;
typedef __bf16 bf16x8 __attribute__((ext_vector_type(8)));
typedef float f32x4 __attribute__((ext_vector_type(4)));
typedef unsigned short u16x8 __attribute__((ext_vector_type(8)));

__device__ __forceinline__ u16 f2bf(float f) {
  unsigned u = __builtin_bit_cast(unsigned, f);
  u += 0x7fffu + ((u >> 16) & 1u);
  return (u16)(u >> 16);
}
__device__ __forceinline__ float b2f(u16 h) {
  return __builtin_bit_cast(float, (unsigned)h << 16);
}

// ---------------------------------------------------------------------------
// Weight conversion: q_w (scaled by C^-0.5) + k_w -> wqk [1024,512] bf16,
// v_w -> wv, p_w -> wp. blockIdx.y==4 builds the combined qk bias (f32).
// ---------------------------------------------------------------------------
__global__ __launch_bounds__(256) void cvt_kernel(const float* __restrict__ qw, const float* __restrict__ kw,
                                                  const float* __restrict__ vw, const float* __restrict__ pw,
                                                  const float* __restrict__ qb, const float* __restrict__ kb,
                                                  u16* __restrict__ wqk, u16* __restrict__ wv,
                                                  u16* __restrict__ wp, float* __restrict__ qkb,
                                                  float scale) {
  if (blockIdx.y == 4) {
    int i = blockIdx.x * 256 + threadIdx.x;
    if (i < 512) qkb[i] = qb[i] * scale;
    else if (i < 1024) qkb[i] = kb[i - 512];
    return;
  }
  const float* s;
  u16* o;
  float sc = 1.f;
  switch (blockIdx.y) {
    case 0: s = qw; o = wqk; sc = scale; break;
    case 1: s = kw; o = wqk + 262144; break;
    case 2: s = vw; o = wv; break;
    default: s = pw; o = wp; break;
  }
  int i = (blockIdx.x * 256 + threadIdx.x) * 4;
  float4 v = *(const float4*)(s + i);
  ushort4 pk = { f2bf(v.x * sc), f2bf(v.y * sc), f2bf(v.z * sc), f2bf(v.w * sc) };
  *(ushort4*)&o[i] = pk;
}

// ---------------------------------------------------------------------------
// GroupNorm: x [B,512,1024] f32 -> hn [B,1024,512] bf16 (transposed, k-contig)
// ---------------------------------------------------------------------------
#define GN_ROW 1026  // 1024 + 2 pad (odd word stride -> conflict-free)

__global__ __launch_bounds__(256) void gn_kernel(const float* __restrict__ x, const float* __restrict__ w,
                                                 const float* __restrict__ bias, u16* __restrict__ hn) {
  __shared__ u16 tile[16 * GN_ROW];
  __shared__ float red[18];
  const int tid = threadIdx.x;
  const int bb = blockIdx.x >> 5;
  const int g = blockIdx.x & 31;
  const float4* xb = (const float4*)(x + ((size_t)bb * 512 + (size_t)g * 16) * 1024);

  float s = 0.f, sq = 0.f;
#pragma unroll
  for (int j = 0; j < 16; ++j) {
    float4 v = xb[j * 256 + tid];
    s += v.x + v.y + v.z + v.w;
    sq += v.x * v.x + v.y * v.y + v.z * v.z + v.w * v.w;
    int base = j * GN_ROW + tid * 4;
    ushort2 p0 = { f2bf(v.x), f2bf(v.y) };
    ushort2 p1 = { f2bf(v.z), f2bf(v.w) };
    *(ushort2*)&tile[base] = p0;
    *(ushort2*)&tile[base + 2] = p1;
  }
#pragma unroll
  for (int o = 32; o; o >>= 1) {
    s += __shfl_down(s, o, 64);
    sq += __shfl_down(sq, o, 64);
  }
  const int wv = tid >> 6;
  if ((tid & 63) == 0) { red[wv] = s; red[wv + 4] = sq; }
  __syncthreads();
  if (tid == 0) {
    float S = red[0] + red[1] + red[2] + red[3];
    float Q = red[4] + red[5] + red[6] + red[7];
    float mean = S * (1.f / 16384.f);
    float var = Q * (1.f / 16384.f) - mean * mean;
    red[16] = mean;
    red[17] = rsqrtf(var + 1e-5f);
  }
  __syncthreads();
  const float mean = red[16], rstd = red[17];
  const int c0 = g * 16;

  float wf[16], bf_[16];
#pragma unroll
  for (int c = 0; c < 16; ++c) {
    float wc = w[c0 + c];
    wf[c] = wc * rstd;
    bf_[c] = bias[c0 + c] - mean * rstd * wc;
  }
#pragma unroll
  for (int it = 0; it < 4; ++it) {
    int hw = it * 256 + tid;
    u16x8 lo{}, hi{};
#pragma unroll
    for (int c = 0; c < 8; ++c) {
      lo[c] = f2bf(b2f(tile[c * GN_ROW + hw]) * wf[c] + bf_[c]);
      hi[c] = f2bf(b2f(tile[(c + 8) * GN_ROW + hw]) * wf[c + 8] + bf_[c + 8]);
    }
    u16* dst = hn + ((size_t)bb * 1024 + hw) * 512 + c0;
    *(u16x8*)dst = lo;
    *(u16x8*)(dst + 8) = hi;
  }
}

// ---------------------------------------------------------------------------
// NT GEMM, NO-LDS: D[m,n] = sum_k A[m,k]*Bt[n,k] + bias_m + bias_n + res.
// R7: operands are L2-resident (FETCH evidence R6); every LDS-staged variant
// (R1/R3/R5/R6) pinned at ~6.7 TB/s logical staging with ALL pipes idle ->
// the intra-block barrier coupling serialized the CU to memory latency.
// Here each wave loads its MFMA fragments DIRECTLY global->VGPR (the frag
// layout row=base+(lane&15), 16B chunk at k0+(lane>>4)*8 is a legal 16-line
// coalesced pattern), 1-deep register prefetch, ZERO barriers, zero LDS.
// Waves are fully independent latency-hiding streams. 2x byte redundancy
// (2 waves share each tile line) is absorbed by L1/L2 headroom.
// 128x128 tile, BK=32, 4 waves of 64x64. XCD swizzle kept (L2 locality).
// ---------------------------------------------------------------------------
template <typename OutT>
__global__ __launch_bounds__(256) void gemm_nt(const u16* __restrict__ A, const u16* __restrict__ Bt,
                                               OutT* __restrict__ C, const float* __restrict__ bias_m,
                                               const float* __restrict__ bias_n, const float* __restrict__ res,
                                               int K, int lda, int ldb, int ldc,
                                               size_t sA, size_t sB, size_t sC, size_t sRes,
                                               int T, int lognbx) {
  // --- XCD-swizzle decode ---
  int fi = blockIdx.x;
  const int halfT = T << 3;
  const int h = (fi >= halfT);
  fi -= h * halfT;
  const int tile = fi >> 3;
  const int zb = (fi & 7) + (h << 3);
  const int bx = tile & ((1 << lognbx) - 1);
  const int by = tile >> lognbx;

  const int tid = threadIdx.x;
  const int lane = tid & 63;
  const int wave = tid >> 6;
  const int wm = wave >> 1, wn = wave & 1;
  const int tm = by * 128, tn = bx * 128;
  const int q = lane >> 4, r = lane & 15;

  const u16* Ab = A + (size_t)zb * sA;
  const u16* Bb = Bt + (size_t)zb * sB;

  // per-lane fragment pointers: row = tile_base + sub*16 + r, chunk q*8
  const u16* pa[4];
  const u16* pb[4];
#pragma unroll
  for (int mt = 0; mt < 4; ++mt) {
    pa[mt] = Ab + (size_t)(tm + wm * 64 + mt * 16 + r) * lda + q * 8;
    pb[mt] = Bb + (size_t)(tn + wn * 64 + mt * 16 + r) * ldb + q * 8;
  }

  f32x4 acc[4][4] = {};
  bf16x8 ca[4], cb[4];
#pragma unroll
  for (int i = 0; i < 4; ++i) {
    ca[i] = *(const bf16x8*)(const void*)pa[i];
    cb[i] = *(const bf16x8*)(const void*)pb[i];
  }

  const int nk = K >> 5;
  for (int k = 1; k < nk; ++k) {
    bf16x8 na[4], nb[4];
    const int k0 = k << 5;
#pragma unroll
    for (int i = 0; i < 4; ++i) {
      na[i] = *(const bf16x8*)(const void*)(pa[i] + k0);
      nb[i] = *(const bf16x8*)(const void*)(pb[i] + k0);
    }
#pragma unroll
    for (int mt = 0; mt < 4; ++mt)
#pragma unroll
      for (int nt = 0; nt < 4; ++nt)
        acc[mt][nt] = __builtin_amdgcn_mfma_f32_16x16x32_bf16(ca[mt], cb[nt], acc[mt][nt], 0, 0, 0);
#pragma unroll
    for (int i = 0; i < 4; ++i) {
      ca[i] = na[i];
      cb[i] = nb[i];
    }
  }
#pragma unroll
  for (int mt = 0; mt < 4; ++mt)
#pragma unroll
    for (int nt = 0; nt < 4; ++nt)
      acc[mt][nt] = __builtin_amdgcn_mfma_f32_16x16x32_bf16(ca[mt], cb[nt], acc[mt][nt], 0, 0, 0);

  OutT* Cb = C + (size_t)zb * sC;
  const float* Rb = res ? res + (size_t)zb * sRes : nullptr;
#pragma unroll
  for (int mt = 0; mt < 4; ++mt) {
#pragma unroll
    for (int nt = 0; nt < 4; ++nt) {
      const int col = tn + wn * 64 + nt * 16 + r;
      const float bn = bias_n ? bias_n[col] : 0.f;
#pragma unroll
      for (int reg = 0; reg < 4; ++reg) {
        const int row = tm + wm * 64 + mt * 16 + q * 4 + reg;
        float v = acc[mt][nt][reg];
        const float bm = bias_m ? bias_m[row] : 0.f;
        v = v + bm + bn;
        const size_t idx = (size_t)row * ldc + col;
        if (Rb) v += Rb[idx];
        if constexpr (__is_same(OutT, u16)) Cb[idx] = f2bf(v);
        else Cb[idx] = v;
      }
    }
  }
}

// ---------------------------------------------------------------------------
// Row softmax, in place on bf16 [rows,1024]; one wave per row, no barriers.
// ---------------------------------------------------------------------------
__global__ __launch_bounds__(256) void softmax_kernel(u16* __restrict__ S) {
  const int row = blockIdx.x * 4 + (threadIdx.x >> 6);
  const int lane = threadIdx.x & 63;
  u16* p = S + (size_t)row * 1024;
  u16x8 a = *(const u16x8*)(p + lane * 8);
  u16x8 b = *(const u16x8*)(p + 512 + lane * 8);
  float va[8], vb[8];
  float m = -3.0e38f;
#pragma unroll
  for (int j = 0; j < 8; ++j) {
    va[j] = b2f(a[j]);
    vb[j] = b2f(b[j]);
    m = fmaxf(m, fmaxf(va[j], vb[j]));
  }
#pragma unroll
  for (int o = 32; o; o >>= 1) m = fmaxf(m, __shfl_xor(m, o, 64));
  float s = 0.f;
#pragma unroll
  for (int j = 0; j < 8; ++j) {
    va[j] = __expf(va[j] - m);
    vb[j] = __expf(vb[j] - m);
    s += va[j] + vb[j];
  }
#pragma unroll
  for (int o = 32; o; o >>= 1) s += __shfl_xor(s, o, 64);
  const float inv = 1.f / s;
  u16x8 oa, ob;
#pragma unroll
  for (int j = 0; j < 8; ++j) {
    oa[j] = f2bf(va[j] * inv);
    ob[j] = f2bf(vb[j] * inv);
  }
  *(u16x8*)(p + lane * 8) = oa;
  *(u16x8*)(p + 512 + lane * 8) = ob;
}

// ---------------------------------------------------------------------------
extern "C" void kernel_launch(void* const* d_in, const int* in_sizes, int n_in,
                              void* d_out, int out_size, void* d_ws, size_t ws_size,
                              hipStream_t stream) {
  const float* x = (const float*)d_in[0];
  const float* gn_w = (const float*)d_in[2];
  const float* gn_b = (const float*)d_in[3];
  const float* q_w = (const float*)d_in[4];
  const float* q_b = (const float*)d_in[5];
  const float* k_w = (const float*)d_in[6];
  const float* k_b = (const float*)d_in[7];
  const float* v_w = (const float*)d_in[8];
  const float* v_b = (const float*)d_in[9];
  const float* p_w = (const float*)d_in[10];
  const float* p_b = (const float*)d_in[11];
  float* out = (float*)d_out;

  // workspace layout (u16 elements)
  u16* wqk = (u16*)d_ws;               // [1024,512]  (q scaled | k)
  u16* wv = wqk + 524288;              // [512,512]
  u16* wp = wv + 262144;               // [512,512]
  float* qkb = (float*)(wp + 262144);  // [1024] f32 combined bias
  u16* hn = wp + 262144 + 2048;        // [16,1024,512]
  u16* qkt = hn + 8388608;             // [16,1024,1024]  Q^T (scaled) | K^T
  u16* vv = qkt + 16777216;            // [16,512,1024]   V
  u16* ot = vv + 8388608;              // [16,1024,512]   O^T
  u16* Sb = ot + 8388608;              // [16,1024,1024]  scores / probs

  const float inv_sqrt_c = 0.044194173824159216f;  // 512^-0.5
  const size_t sHN = 524288, sS = 1048576;

  cvt_kernel<<<dim3(256, 5), 256, 0, stream>>>(q_w, k_w, v_w, p_w, q_b, k_b, wqk, wv, wp, qkb, inv_sqrt_c);
  gn_kernel<<<512, 256, 0, stream>>>(x, gn_w, gn_b, hn);

  // QK^T[b] = Hn^T . [Wq';Wk]^T + qkb   [1024,1024]   T=64 tiles (8x8), nbx=8
  gemm_nt<u16><<<dim3(16 * 64), 256, 0, stream>>>(hn, wqk, qkt, nullptr, qkb, nullptr,
                                                  512, 512, 512, 1024, sHN, 0, sS, 0, 64, 3);
  // V[b] = Wv . Hn + v_b                 [512,1024]   T=32 tiles (4x8), nbx=8
  gemm_nt<u16><<<dim3(16 * 32), 256, 0, stream>>>(wv, hn, vv, v_b, nullptr, nullptr,
                                                  512, 512, 512, 1024, 0, sHN, sHN, 0, 32, 3);
  // S[b] = Q'^T . K                      [1024,1024]  T=64 tiles (8x8), nbx=8
  gemm_nt<u16><<<dim3(16 * 64), 256, 0, stream>>>(qkt, qkt + 512, Sb, nullptr, nullptr, nullptr,
                                                  512, 1024, 1024, 1024, sS, sS, sS, 0, 64, 3);
  softmax_kernel<<<4096, 256, 0, stream>>>(Sb);
  // O^T[b] = P . V^T                     [1024,512]   T=32 tiles (8x4), nbx=4
  gemm_nt<u16><<<dim3(16 * 32), 256, 0, stream>>>(Sb, vv, ot, nullptr, nullptr, nullptr,
                                                  1024, 1024, 1024, 512, sS, sHN, sHN, 0, 32, 2);
  // out[b] = Wp . O + p_b + x            [512,1024] f32  T=32 tiles (4x8), nbx=8
  gemm_nt<float><<<dim3(16 * 32), 256, 0, stream>>>(wp, ot, out, p_b, nullptr, x,
                                                    512, 512, 512, 1024, 0, sHN, sHN, sHN, 32, 3);
}

// Round 8
// 256.518 us; speedup vs baseline: 1.6390x; 1.6390x over previous
//
#include <hip/hip_runtime.h>

typedef unsigned short u16;
typedef __bf16 bf16x8 __attribute__((ext_vector_type(8)));
typedef float f32x4 __attribute__((ext_vector_type(4)));
typedef unsigned short u16x8 __attribute__((ext_vector_type(8)));

__device__ __forceinline__ u16 f2bf(float f) {
  unsigned u = __builtin_bit_cast(unsigned, f);
  u += 0x7fffu + ((u >> 16) & 1u);
  return (u16)(u >> 16);
}
__device__ __forceinline__ float b2f(u16 h) {
  return __builtin_bit_cast(float, (unsigned)h << 16);
}

// ---------------------------------------------------------------------------
// Weight conversion: q_w (scaled by C^-0.5) + k_w -> wqk [1024,512] bf16,
// v_w -> wv, p_w -> wp. blockIdx.y==4 builds the combined qk bias (f32).
// ---------------------------------------------------------------------------
__global__ __launch_bounds__(256) void cvt_kernel(const float* __restrict__ qw, const float* __restrict__ kw,
                                                  const float* __restrict__ vw, const float* __restrict__ pw,
                                                  const float* __restrict__ qb, const float* __restrict__ kb,
                                                  u16* __restrict__ wqk, u16* __restrict__ wv,
                                                  u16* __restrict__ wp, float* __restrict__ qkb,
                                                  float scale) {
  if (blockIdx.y == 4) {
    int i = blockIdx.x * 256 + threadIdx.x;
    if (i < 512) qkb[i] = qb[i] * scale;
    else if (i < 1024) qkb[i] = kb[i - 512];
    return;
  }
  const float* s;
  u16* o;
  float sc = 1.f;
  switch (blockIdx.y) {
    case 0: s = qw; o = wqk; sc = scale; break;
    case 1: s = kw; o = wqk + 262144; break;
    case 2: s = vw; o = wv; break;
    default: s = pw; o = wp; break;
  }
  int i = (blockIdx.x * 256 + threadIdx.x) * 4;
  float4 v = *(const float4*)(s + i);
  ushort4 pk = { f2bf(v.x * sc), f2bf(v.y * sc), f2bf(v.z * sc), f2bf(v.w * sc) };
  *(ushort4*)&o[i] = pk;
}

// ---------------------------------------------------------------------------
// GroupNorm: x [B,512,1024] f32 -> hn [B,1024,512] bf16 (transposed, k-contig)
// ---------------------------------------------------------------------------
#define GN_ROW 1026  // 1024 + 2 pad (odd word stride -> conflict-free)

__global__ __launch_bounds__(256) void gn_kernel(const float* __restrict__ x, const float* __restrict__ w,
                                                 const float* __restrict__ bias, u16* __restrict__ hn) {
  __shared__ u16 tile[16 * GN_ROW];
  __shared__ float red[18];
  const int tid = threadIdx.x;
  const int bb = blockIdx.x >> 5;
  const int g = blockIdx.x & 31;
  const float4* xb = (const float4*)(x + ((size_t)bb * 512 + (size_t)g * 16) * 1024);

  float s = 0.f, sq = 0.f;
#pragma unroll
  for (int j = 0; j < 16; ++j) {
    float4 v = xb[j * 256 + tid];
    s += v.x + v.y + v.z + v.w;
    sq += v.x * v.x + v.y * v.y + v.z * v.z + v.w * v.w;
    int base = j * GN_ROW + tid * 4;
    ushort2 p0 = { f2bf(v.x), f2bf(v.y) };
    ushort2 p1 = { f2bf(v.z), f2bf(v.w) };
    *(ushort2*)&tile[base] = p0;
    *(ushort2*)&tile[base + 2] = p1;
  }
#pragma unroll
  for (int o = 32; o; o >>= 1) {
    s += __shfl_down(s, o, 64);
    sq += __shfl_down(sq, o, 64);
  }
  const int wv = tid >> 6;
  if ((tid & 63) == 0) { red[wv] = s; red[wv + 4] = sq; }
  __syncthreads();
  if (tid == 0) {
    float S = red[0] + red[1] + red[2] + red[3];
    float Q = red[4] + red[5] + red[6] + red[7];
    float mean = S * (1.f / 16384.f);
    float var = Q * (1.f / 16384.f) - mean * mean;
    red[16] = mean;
    red[17] = rsqrtf(var + 1e-5f);
  }
  __syncthreads();
  const float mean = red[16], rstd = red[17];
  const int c0 = g * 16;

  float wf[16], bf_[16];
#pragma unroll
  for (int c = 0; c < 16; ++c) {
    float wc = w[c0 + c];
    wf[c] = wc * rstd;
    bf_[c] = bias[c0 + c] - mean * rstd * wc;
  }
#pragma unroll
  for (int it = 0; it < 4; ++it) {
    int hw = it * 256 + tid;
    u16x8 lo{}, hi{};
#pragma unroll
    for (int c = 0; c < 8; ++c) {
      lo[c] = f2bf(b2f(tile[c * GN_ROW + hw]) * wf[c] + bf_[c]);
      hi[c] = f2bf(b2f(tile[(c + 8) * GN_ROW + hw]) * wf[c + 8] + bf_[c + 8]);
    }
    u16* dst = hn + ((size_t)bb * 1024 + hw) * 512 + c0;
    *(u16x8*)dst = lo;
    *(u16x8*)(dst + 8) = hi;
  }
}

// ---------------------------------------------------------------------------
// NT GEMM: D[m,n] = sum_k A[m,k]*Bt[n,k] + bias_m[m] + bias_n[n] + res[m,n]
// Templated tile BMxBN; TPB = BM*BN/64 threads, waves of 64x64 in a
// (BM/64)x(BN/64) grid; BK=32; mfma 16x16x32 bf16.
// Staging: buffer_load->VGPR->ds_write (R6 path, measured AT the ~10.6
// B/cyc/CU vector-load wall), double-buffered LDS, swizzle slot =
// chunk ^ ((row>>1)&3) conflict-free for ds_write_b128 / ds_read_b128.
// R8: BM=BN=256 (1024 thr, 64 KB LDS, VGPR<=128 via launch_bounds) for the
// square GEMMs halves staged bytes per FLOP -> halves their wall time.
// XCD swizzle: all tiles of batch z on XCD z%8 (verified R3).
// ---------------------------------------------------------------------------
template <int BM, int BN, int MINW, typename OutT>
__global__ __launch_bounds__(BM * BN / 64, MINW) void gemm_nt(
    const u16* __restrict__ A, const u16* __restrict__ Bt, OutT* __restrict__ C,
    const float* __restrict__ bias_m, const float* __restrict__ bias_n, const float* __restrict__ res,
    int K, int lda, int ldb, int ldc, size_t sA, size_t sB, size_t sC, size_t sRes,
    int T, int lognbx) {
  constexpr int TPB = BM * BN / 64;
  constexpr int WGN = BN / 64;
  constexpr int ASLOT = 4 * BM / TPB;  // dwordx4 staging slots per thread (A)
  constexpr int BSLOT = 4 * BN / TPB;
  __shared__ u16 lsA[2][BM * 32];
  __shared__ u16 lsB[2][BN * 32];

  // --- XCD-swizzle decode ---
  int fi = blockIdx.x;
  const int halfT = T << 3;
  const int h = (fi >= halfT);
  fi -= h * halfT;
  const int tile = fi >> 3;
  const int zb = (fi & 7) + (h << 3);
  const int bx = tile & ((1 << lognbx) - 1);
  const int by = tile >> lognbx;

  const int tid = threadIdx.x;
  const int lane = tid & 63;
  const int wave = tid >> 6;
  const int wm = wave / WGN, wn = wave % WGN;
  const int tm = by * BM, tn = bx * BN;
  const u16* Ab = A + (size_t)zb * sA;
  const u16* Bb = Bt + (size_t)zb * sB;

  f32x4 acc[4][4] = {};
  const int q = lane >> 4, r = lane & 15;

  // staging maps: slot e -> row=e>>2, 16B chunk g=e&3, LDS slot g^((row>>1)&3)
  const u16* pA[ASLOT];
  const u16* pB[BSLOT];
  int waA[ASLOT], waB[BSLOT];
#pragma unroll
  for (int i = 0; i < ASLOT; ++i) {
    int e = tid + i * TPB;
    int ra = e >> 2, g = e & 3;
    pA[i] = Ab + (size_t)(tm + ra) * lda + g * 8;
    waA[i] = ra * 32 + (g ^ ((ra >> 1) & 3)) * 8;
  }
#pragma unroll
  for (int i = 0; i < BSLOT; ++i) {
    int e = tid + i * TPB;
    int ra = e >> 2, g = e & 3;
    pB[i] = Bb + (size_t)(tn + ra) * ldb + g * 8;
    waB[i] = ra * 32 + (g ^ ((ra >> 1) & 3)) * 8;
  }

  u16x8 rA[ASLOT], rB[BSLOT];
#pragma unroll
  for (int i = 0; i < ASLOT; ++i) rA[i] = *(const u16x8*)pA[i];
#pragma unroll
  for (int i = 0; i < BSLOT; ++i) rB[i] = *(const u16x8*)pB[i];
#pragma unroll
  for (int i = 0; i < ASLOT; ++i) *(u16x8*)&lsA[0][waA[i]] = rA[i];
#pragma unroll
  for (int i = 0; i < BSLOT; ++i) *(u16x8*)&lsB[0][waB[i]] = rB[i];
  __syncthreads();

  // fragment read offsets (swizzled)
  int offA[4], offB[4];
#pragma unroll
  for (int mt = 0; mt < 4; ++mt) {
    int rowa = wm * 64 + mt * 16 + r;
    offA[mt] = rowa * 32 + (q ^ ((rowa >> 1) & 3)) * 8;
    int rowb = wn * 64 + mt * 16 + r;
    offB[mt] = rowb * 32 + (q ^ ((rowb >> 1) & 3)) * 8;
  }

  const int nk = K >> 5;
  for (int k = 0; k < nk; ++k) {
    const int cur = k & 1;
    if (k + 1 < nk) {
      const int k0 = (k + 1) << 5;
#pragma unroll
      for (int i = 0; i < ASLOT; ++i) rA[i] = *(const u16x8*)(pA[i] + k0);
#pragma unroll
      for (int i = 0; i < BSLOT; ++i) rB[i] = *(const u16x8*)(pB[i] + k0);
    }
    bf16x8 af[4], bfv[4];
#pragma unroll
    for (int mt = 0; mt < 4; ++mt) {
      af[mt] = *(const bf16x8*)(const void*)&lsA[cur][offA[mt]];
      bfv[mt] = *(const bf16x8*)(const void*)&lsB[cur][offB[mt]];
    }
#pragma unroll
    for (int mt = 0; mt < 4; ++mt)
#pragma unroll
      for (int nt = 0; nt < 4; ++nt)
        acc[mt][nt] = __builtin_amdgcn_mfma_f32_16x16x32_bf16(af[mt], bfv[nt], acc[mt][nt], 0, 0, 0);
    if (k + 1 < nk) {
      const int nxt = cur ^ 1;
#pragma unroll
      for (int i = 0; i < ASLOT; ++i) *(u16x8*)&lsA[nxt][waA[i]] = rA[i];
#pragma unroll
      for (int i = 0; i < BSLOT; ++i) *(u16x8*)&lsB[nxt][waB[i]] = rB[i];
    }
    __syncthreads();
  }

  OutT* Cb = C + (size_t)zb * sC;
  const float* Rb = res ? res + (size_t)zb * sRes : nullptr;
#pragma unroll
  for (int mt = 0; mt < 4; ++mt) {
#pragma unroll
    for (int nt = 0; nt < 4; ++nt) {
      const int col = tn + wn * 64 + nt * 16 + r;
      const float bn = bias_n ? bias_n[col] : 0.f;
#pragma unroll
      for (int reg = 0; reg < 4; ++reg) {
        const int row = tm + wm * 64 + mt * 16 + q * 4 + reg;
        float v = acc[mt][nt][reg];
        const float bm = bias_m ? bias_m[row] : 0.f;
        v = v + bm + bn;
        const size_t idx = (size_t)row * ldc + col;
        if (Rb) v += Rb[idx];
        if constexpr (__is_same(OutT, u16)) Cb[idx] = f2bf(v);
        else Cb[idx] = v;
      }
    }
  }
}

// ---------------------------------------------------------------------------
// Row softmax, in place on bf16 [rows,1024]; one wave per row, no barriers.
// ---------------------------------------------------------------------------
__global__ __launch_bounds__(256) void softmax_kernel(u16* __restrict__ S) {
  const int row = blockIdx.x * 4 + (threadIdx.x >> 6);
  const int lane = threadIdx.x & 63;
  u16* p = S + (size_t)row * 1024;
  u16x8 a = *(const u16x8*)(p + lane * 8);
  u16x8 b = *(const u16x8*)(p + 512 + lane * 8);
  float va[8], vb[8];
  float m = -3.0e38f;
#pragma unroll
  for (int j = 0; j < 8; ++j) {
    va[j] = b2f(a[j]);
    vb[j] = b2f(b[j]);
    m = fmaxf(m, fmaxf(va[j], vb[j]));
  }
#pragma unroll
  for (int o = 32; o; o >>= 1) m = fmaxf(m, __shfl_xor(m, o, 64));
  float s = 0.f;
#pragma unroll
  for (int j = 0; j < 8; ++j) {
    va[j] = __expf(va[j] - m);
    vb[j] = __expf(vb[j] - m);
    s += va[j] + vb[j];
  }
#pragma unroll
  for (int o = 32; o; o >>= 1) s += __shfl_xor(s, o, 64);
  const float inv = 1.f / s;
  u16x8 oa, ob;
#pragma unroll
  for (int j = 0; j < 8; ++j) {
    oa[j] = f2bf(va[j] * inv);
    ob[j] = f2bf(vb[j] * inv);
  }
  *(u16x8*)(p + lane * 8) = oa;
  *(u16x8*)(p + 512 + lane * 8) = ob;
}

// ---------------------------------------------------------------------------
extern "C" void kernel_launch(void* const* d_in, const int* in_sizes, int n_in,
                              void* d_out, int out_size, void* d_ws, size_t ws_size,
                              hipStream_t stream) {
  const float* x = (const float*)d_in[0];
  const float* gn_w = (const float*)d_in[2];
  const float* gn_b = (const float*)d_in[3];
  const float* q_w = (const float*)d_in[4];
  const float* q_b = (const float*)d_in[5];
  const float* k_w = (const float*)d_in[6];
  const float* k_b = (const float*)d_in[7];
  const float* v_w = (const float*)d_in[8];
  const float* v_b = (const float*)d_in[9];
  const float* p_w = (const float*)d_in[10];
  const float* p_b = (const float*)d_in[11];
  float* out = (float*)d_out;

  // workspace layout (u16 elements)
  u16* wqk = (u16*)d_ws;               // [1024,512]  (q scaled | k)
  u16* wv = wqk + 524288;              // [512,512]
  u16* wp = wv + 262144;               // [512,512]
  float* qkb = (float*)(wp + 262144);  // [1024] f32 combined bias
  u16* hn = wp + 262144 + 2048;        // [16,1024,512]
  u16* qkt = hn + 8388608;             // [16,1024,1024]  Q^T (scaled) | K^T
  u16* vv = qkt + 16777216;            // [16,512,1024]   V
  u16* ot = vv + 8388608;              // [16,1024,512]   O^T
  u16* Sb = ot + 8388608;              // [16,1024,1024]  scores / probs

  const float inv_sqrt_c = 0.044194173824159216f;  // 512^-0.5
  const size_t sHN = 524288, sS = 1048576;

  cvt_kernel<<<dim3(256, 5), 256, 0, stream>>>(q_w, k_w, v_w, p_w, q_b, k_b, wqk, wv, wp, qkb, inv_sqrt_c);
  gn_kernel<<<512, 256, 0, stream>>>(x, gn_w, gn_b, hn);

  // QK^T[b] = Hn^T . [Wq';Wk]^T + qkb   [1024,1024]  256x256, 16 tiles, nbx=4
  gemm_nt<256, 256, 4, u16><<<256, 1024, 0, stream>>>(hn, wqk, qkt, nullptr, qkb, nullptr,
                                                      512, 512, 512, 1024, sHN, 0, sS, 0, 16, 2);
  // V[b] = Wv . Hn + v_b                 [512,1024]  128x128, 32 tiles (4x8), nbx=8
  gemm_nt<128, 128, 3, u16><<<512, 256, 0, stream>>>(wv, hn, vv, v_b, nullptr, nullptr,
                                                     512, 512, 512, 1024, 0, sHN, sHN, 0, 32, 3);
  // S[b] = Q'^T . K                      [1024,1024] 256x256, 16 tiles, nbx=4
  gemm_nt<256, 256, 4, u16><<<256, 1024, 0, stream>>>(qkt, qkt + 512, Sb, nullptr, nullptr, nullptr,
                                                      512, 1024, 1024, 1024, sS, sS, sS, 0, 16, 2);
  softmax_kernel<<<4096, 256, 0, stream>>>(Sb);
  // O^T[b] = P . V^T                     [1024,512]  128x128, 32 tiles (8x4), nbx=4
  gemm_nt<128, 128, 3, u16><<<512, 256, 0, stream>>>(Sb, vv, ot, nullptr, nullptr, nullptr,
                                                     1024, 1024, 1024, 512, sS, sHN, sHN, 0, 32, 2);
  // out[b] = Wp . O + p_b + x            [512,1024] f32  128x128, 32 tiles (4x8), nbx=8
  gemm_nt<128, 128, 3, float><<<512, 256, 0, stream>>>(wp, ot, out, p_b, nullptr, x,
                                                       512, 512, 512, 1024, 0, sHN, sHN, sHN, 32, 3);
}